// Round 8
// baseline (402.280 us; speedup 1.0000x reference)
//
#include <hip/hip_runtime.h>
#include <stdint.h>

#define B_  256
#define T_  512
#define H_  128
#define NSW 6

typedef __bf16 bf2_t  __attribute__((ext_vector_type(2)));
typedef int    i32x4  __attribute__((ext_vector_type(4)));
typedef float  f32x4  __attribute__((ext_vector_type(4)));

// float -> bf16 round-to-nearest-even
__device__ __forceinline__ unsigned short f2bf(float f){
  unsigned u = __float_as_uint(f);
  unsigned r = u + 0x7FFFu + ((u >> 16) & 1u);
  return (unsigned short)(r >> 16);
}
__device__ __forceinline__ unsigned pack2(float a, float b){
  return (unsigned)f2bf(a) | ((unsigned)f2bf(b) << 16);
}
__device__ __forceinline__ float dot2bf(unsigned wpair, unsigned hpair, float acc){
  return __builtin_amdgcn_fdot2_f32_bf16(__builtin_bit_cast(bf2_t, wpair),
                                         __builtin_bit_cast(bf2_t, hpair), acc, false);
}
__device__ __forceinline__ void lds_barrier(){
  asm volatile("s_waitcnt lgkmcnt(0)\ns_barrier" ::: "memory");
}

// Per-row symmetric int8 quantization into MFMA B-fragment order for
// mfma_i32_16x16x64_i8 (W^T). Tile (s, g', w) covers rows i = 16w..16w+15 of
// gate g'; half m covers k = 64m..64m+63.
// uint4 idx = ((s*24 + g'*8 + w)*2 + m)*64 + q*16 + c holds int8 of
//   W_g'[s][i = 16w + c][k = m*64 + q*16 + e]  (byte e of word e>>2)
// A-side (h) uses the same (quad,byte)<->k convention -> any HW k-permutation
// cancels. scales[s*384 + g'*128 + i] = rowmax / (127*127)
__global__ __launch_bounds__(256) void pack_weights_i8(const float* __restrict__ Wr,
                                                       const float* __restrict__ Wz,
                                                       const float* __restrict__ Wn,
                                                       uint4* __restrict__ dst,
                                                       float* __restrict__ scales){
  int idx = blockIdx.x * 256 + threadIdx.x;     // (s, row384)
  if (idx >= NSW * 384) return;
  int s   = idx / 384;
  int row = idx % 384;
  int gp  = row >> 7;                            // gate 0..2
  int i   = row & 127;                           // output row within gate
  const float* W = (gp == 0) ? Wr : (gp == 1) ? Wz : Wn;
  const float* src = W + (size_t)s * (H_*H_) + (size_t)i * H_;
  float amax = 0.f;
  for (int j = 0; j < H_; ++j) amax = fmaxf(amax, fabsf(src[j]));
  amax = fmaxf(amax, 1e-20f);
  float inv = 127.f / amax;
  scales[idx] = amax / 16129.f;                 // amax / 127^2
  int w = i >> 4, c = i & 15;
  for (int m = 0; m < 2; ++m){
    for (int q = 0; q < 4; ++q){
      unsigned bw[4] = {0, 0, 0, 0};
      for (int e = 0; e < 16; ++e){
        int k = m * 64 + q * 16 + e;
        int v = (int)rintf(src[k] * inv);
        v = v > 127 ? 127 : (v < -127 ? -127 : v);
        bw[e >> 2] |= ((unsigned)(v & 0xFF)) << (8 * (e & 3));
      }
      dst[((size_t)((s * 24 + gp * 8 + w) * 2 + m)) * 64 + q * 16 + c] =
        make_uint4(bw[0], bw[1], bw[2], bw[3]);
    }
  }
}

// 512 threads = 8 waves. Transposed MFMA: A = h (row 0 only), B = W^T.
// Round-8 deltas (DS-pipe eviction):
//  - dequant scales + b_n live in 24 REGISTERS (f32x4 scb[6]), selected by the
//    existing switch(sc) with compile-time indices -> zero per-step DS reads
//    for scale/bias, sidn-prefetch logic removed.
//  - r/z biases are additive to x -> folded into x-tilde at the chunk boundary
//    (s_brz read per tt, amortized).
//  - h-frag reads exec-masked to colv lanes; x-tilde read masked to L<16
//    (masked-out lanes consume no LDS beats).
//  - MFMA k-halves independent (a.x + c.x) -> one less dependent-MFMA latency.
__global__ __launch_bounds__(512, 2) void gru_run(const float* __restrict__ stim,
    const int*   __restrict__ swid,  const float* __restrict__ mask,
    const float* __restrict__ Win,   const float* __restrict__ binp,
    const float* __restrict__ b_hr,  const float* __restrict__ b_hz, const float* __restrict__ b_hn,
    const float* __restrict__ Wo,    const float* __restrict__ bo,
    const uint4* __restrict__ Wpk,   const float* __restrict__ Wsc,
    float* __restrict__ out)
{
  const int b   = blockIdx.x;
  const int tid = threadIdx.x;
  const int w   = tid >> 6;          // 0..7
  const int L   = tid & 63;

  __shared__ uint4          s_stim2[T_];            // 8 KB   bf16 stim pairs
  __shared__ unsigned       s_sm[T_];               // 2 KB   {bf16 mask <<16 | sid}
  __shared__ __align__(16) float2 s_brz[NSW][H_];     // 6 KB   {b_hr, b_hz} per (s,row)
  __shared__ __align__(16) f32x4  s_xt[32][H_];       // 64 KB  x-projection chunk (bias-folded)
  __shared__ __align__(16) float2 s_po[32][130];      // 32.5 KB output partials (padded)
  __shared__ __align__(16) char   s_hb8[2][H_];       // linear int8 h slots

  // ---- init LDS ----
  for (int k = tid; k < T_; k += 512){
    const float* sp = stim + (size_t)b * T_ * 8 + (size_t)k * 8;
    uint4 o;
    o.x = pack2(sp[0], sp[1]); o.y = pack2(sp[2], sp[3]);
    o.z = pack2(sp[4], sp[5]); o.w = pack2(sp[6], sp[7]);
    s_stim2[k] = o;
    int ss = swid[(size_t)b * T_ + k];
    ss = ss < 0 ? 0 : (ss > NSW - 1 ? NSW - 1 : ss);
    s_sm[k] = ((unsigned)f2bf(mask[(size_t)b * T_ + k]) << 16) | (unsigned)ss;
  }
  for (int k = tid; k < NSW * H_; k += 512){
    int s = k >> 7, i = k & 127;
    s_brz[s][i] = make_float2(b_hr[s * H_ + i], b_hz[s * H_ + i]);
  }
  if (tid < 64) ((int*)s_hb8)[tid] = 0;          // zero both int8 slots

  // pre-phase x-projection weights: thread handles row hi_p for all 3 gates
  const int hi_p = tid & 127;
  const int tq   = tid >> 7;                     // 0..3: covers t-offsets tq*8..tq*8+7
  unsigned winp[3][4];
  float    binr[3];
  #pragma unroll
  for (int gp = 0; gp < 3; ++gp){
    int row = gp * 128 + hi_p;
    #pragma unroll
    for (int e = 0; e < 4; ++e)
      winp[gp][e] = pack2(Win[(size_t)row * 8 + 2*e], Win[(size_t)row * 8 + 2*e + 1]);
    binr[gp] = binp[row];
  }

  const bool colv = (L & 15) == 0;
  const int  quad = L >> 4;
  const int  hi_  = 16 * w + (L & 15);
  float* outp = out + (size_t)b * T_ * 2;
  const float bo0 = bo[0], bo1 = bo[1];
  float wo0r = 0.f, wo1r = 0.f;
  if (L < 16){ wo0r = Wo[hi_]; wo1r = Wo[H_ + hi_]; }

  // per-lane dequant scales (+ b_n, which sits inside the r-multiplied term):
  // scb[s] = {scl_r, scl_z, scl_n, b_n} for row hi_. Selected by switch(sc)
  // with compile-time indices (stays in registers).
  f32x4 scb[6];
  #pragma unroll
  for (int s = 0; s < 6; ++s){
    scb[s].x = Wsc[s * 384 + hi_];
    scb[s].y = Wsc[s * 384 + 128 + hi_];
    scb[s].z = Wsc[s * 384 + 256 + hi_];
    scb[s].w = b_hn[s * H_ + hi_];
  }

  // ---- preload ALL 6 switch-sets' B fragments (W^T). volatile: cannot be
  //      sunk into the loop or rematerialized. 6 x 6 x uint4 = 144 regs.
  uint4 Bf[6][6];
  #pragma unroll
  for (int s = 0; s < 6; ++s){
    #pragma unroll
    for (int gp = 0; gp < 3; ++gp){
      #pragma unroll
      for (int m = 0; m < 2; ++m){
        const volatile unsigned* vp =
          (const volatile unsigned*)(Wpk + ((size_t)((s * 24 + gp * 8 + w) * 2 + m)) * 64 + L);
        Bf[s][gp*2+m].x = vp[0];
        Bf[s][gp*2+m].y = vp[1];
        Bf[s][gp*2+m].z = vp[2];
        Bf[s][gp*2+m].w = vp[3];
      }
    }
  }

  __syncthreads();

  float hprev = 0.f;
  int   smv = 0;                                 // 64 steps of {mask|sid}, lane L = step

#define MFMA64(A_, B_, C_) __builtin_amdgcn_mfma_i32_16x16x64_i8( \
    __builtin_bit_cast(i32x4, (A_)), __builtin_bit_cast(i32x4, (B_)), (C_), 0, 0, 0)
#define MM(S)                                                                  \
    { i32x4 a, c; const i32x4 zz = {0,0,0,0};                                  \
      a = MFMA64(blo, Bf[S][0], zz); c = MFMA64(bhi, Bf[S][1], zz);            \
      acx0 = a.x + c.x;                                                        \
      a = MFMA64(blo, Bf[S][2], zz); c = MFMA64(bhi, Bf[S][3], zz);            \
      acx1 = a.x + c.x;                                                        \
      a = MFMA64(blo, Bf[S][4], zz); c = MFMA64(bhi, Bf[S][5], zz);            \
      acx2 = a.x + c.x; }

#define REDUCE(TBASE)                                                          \
  {                                                                            \
    int tp = tid >> 4;                                                         \
    int q  = tid & 15;                                                         \
    const f32x4* prow = (const f32x4*)&s_po[tp][0];                            \
    f32x4 a0 = prow[q], a1 = prow[q+16], a2 = prow[q+32], a3 = prow[q+48];     \
    f32x4 sv = (a0 + a1) + (a2 + a3);                                          \
    float p0 = sv.x + sv.z, p1 = sv.y + sv.w;                                  \
    p0 += __shfl_down(p0, 8, 16); p1 += __shfl_down(p1, 8, 16);                \
    p0 += __shfl_down(p0, 4, 16); p1 += __shfl_down(p1, 4, 16);                \
    p0 += __shfl_down(p0, 2, 16); p1 += __shfl_down(p1, 2, 16);                \
    p0 += __shfl_down(p0, 1, 16); p1 += __shfl_down(p1, 1, 16);                \
    if (q == 0)                                                                \
      *(float2*)&outp[((TBASE) + tp) * 2] = make_float2(p0 + bo0, p1 + bo1);   \
  }

  #pragma unroll 1
  for (int t = 0; t < T_; ++t){
    // ---- chunk boundary: reduce previous chunk's outputs + build x̃ chunk ----
    if ((t & 31) == 0){
      if (t > 0) REDUCE(t - 32);
      #pragma unroll
      for (int j = 0; j < 8; ++j){
        int tt = t + tq * 8 + j;
        uint4 sp = s_stim2[tt];
        int sid_tt = (int)(s_sm[tt] & 0xFFFFu);        // wave-uniform
        float2 brz = s_brz[sid_tt][hi_p];
        float x0 = binr[0];
        x0 = dot2bf(winp[0][0], sp.x, x0); x0 = dot2bf(winp[0][1], sp.y, x0);
        x0 = dot2bf(winp[0][2], sp.z, x0); x0 = dot2bf(winp[0][3], sp.w, x0);
        float x1 = binr[1];
        x1 = dot2bf(winp[1][0], sp.x, x1); x1 = dot2bf(winp[1][1], sp.y, x1);
        x1 = dot2bf(winp[1][2], sp.z, x1); x1 = dot2bf(winp[1][3], sp.w, x1);
        float x2 = binr[2];
        x2 = dot2bf(winp[2][0], sp.x, x2); x2 = dot2bf(winp[2][1], sp.y, x2);
        x2 = dot2bf(winp[2][2], sp.z, x2); x2 = dot2bf(winp[2][3], sp.w, x2);
        f32x4 xv;
        xv.x = x0 + brz.x;          // r-gate bias folded
        xv.y = x1 + brz.y;          // z-gate bias folded
        xv.z = x2;                  // b_n NOT foldable (sits inside r * (...))
        xv.w = 0.f;
        s_xt[tq * 8 + j][hi_p] = xv;
      }
      lds_barrier();
    }
    if ((t & 63) == 0) smv = (int)s_sm[t + L];   // 64 steps of {mask|sid} into a VGPR

    // per-step uniform sid/mask via readlane (zero DS)
    int   sm_c = __builtin_amdgcn_readlane(smv, t & 63);
    int   sc   = sm_c & 0xFFFF;
    float mt   = __uint_as_float((unsigned)sm_c & 0xFFFF0000u);

    // A fragments: h_{t-1} linear int8; exec-masked to the 4 colv lanes
    const char* hsrc = &s_hb8[(t + 1) & 1][0];
    uint4 blo = {0, 0, 0, 0}, bhi = {0, 0, 0, 0};
    if (colv){
      blo = *(const uint4*)(hsrc + quad * 16);
      bhi = *(const uint4*)(hsrc + 64 + quad * 16);
    }

    // x̃ for this lane's row (only L<16 uses it; masked read)
    f32x4 xtv = {0.f, 0.f, 0.f, 0.f};
    if (L < 16) xtv = s_xt[t & 31][hi_];

    // matvec + in-register scale/bias select (compile-time scb index)
    int acx0, acx1, acx2;
    f32x4 sclv;
    switch (sc){
      case 0: MM(0); sclv = scb[0]; break;
      case 1: MM(1); sclv = scb[1]; break;
      case 2: MM(2); sclv = scb[2]; break;
      case 3: MM(3); sclv = scb[3]; break;
      case 4: MM(4); sclv = scb[4]; break;
      default: MM(5); sclv = scb[5]; break;
    }

    // dequant + pointwise, fully in-register (lane l<16: h row 16w+l)
    if (L < 16){
      float ar = fmaf((float)acx0, sclv.x, xtv.x);      // includes x + b_r
      float az = fmaf((float)acx1, sclv.y, xtv.y);      // includes x + b_z
      float an = fmaf((float)acx2, sclv.z, sclv.w);     // matvec*scl + b_n
      float r = __builtin_amdgcn_rcpf(1.f + __expf(-ar));
      float z = __builtin_amdgcn_rcpf(1.f + __expf(-az));
      float e = __expf(2.f * fmaf(r, an, xtv.z));       // tanh(a) = 1 - 2/(e^{2a}+1)
      float n = fmaf(-2.f, __builtin_amdgcn_rcpf(e + 1.f), 1.f);
      float hnew = fmaf(z, hprev - n, n);
      float ho   = fmaf(mt, hnew - hprev, hprev);
      hprev = ho;
      float qf = fminf(fmaxf(ho * 127.f, -127.f), 127.f);
      s_hb8[t & 1][hi_] = (char)(int)rintf(qf);          // h byte first (consumers wait on it)
      s_po[t & 31][hi_] = make_float2(wo0r * ho, wo1r * ho);
    }

    lds_barrier();   // the ONLY barrier: h_t visible (and boundary data stable)
  }

  // final chunk's outputs
  REDUCE(T_ - 32);
#undef REDUCE
#undef MM
#undef MFMA64
}

extern "C" void kernel_launch(void* const* d_in, const int* in_sizes, int n_in,
                              void* d_out, int out_size, void* d_ws, size_t ws_size,
                              hipStream_t stream) {
  const float* stim = (const float*)d_in[0];
  const int*   swid = (const int*)  d_in[1];
  const float* mask = (const float*)d_in[2];
  const float* Win  = (const float*)d_in[3];
  const float* binp = (const float*)d_in[4];
  const float* Whr  = (const float*)d_in[5];
  const float* Whz  = (const float*)d_in[6];
  const float* Whn  = (const float*)d_in[7];
  const float* bhr  = (const float*)d_in[8];
  const float* bhz  = (const float*)d_in[9];
  const float* bhn  = (const float*)d_in[10];
  const float* Wo   = (const float*)d_in[11];
  const float* bo   = (const float*)d_in[12];

  uint4* wpk = (uint4*)d_ws;                       // 294912 B packed int8 frags
  float* wsc = (float*)((char*)d_ws + 294912);     // 9216 B row scales

  pack_weights_i8<<<9, 256, 0, stream>>>(Whr, Whz, Whn, wpk, wsc);
  gru_run<<<B_, 512, 0, stream>>>(stim, swid, mask, Win, binp,
                                  bhr, bhz, bhn, Wo, bo, wpk, wsc, (float*)d_out);
}

// Round 9
// 377.852 us; speedup vs baseline: 1.0646x; 1.0646x over previous
//
#include <hip/hip_runtime.h>
#include <stdint.h>

#define B_  256
#define T_  512
#define H_  128
#define NSW 6

typedef __bf16 bf2_t  __attribute__((ext_vector_type(2)));
typedef int    i32x4  __attribute__((ext_vector_type(4)));
typedef float  f32x4  __attribute__((ext_vector_type(4)));

// float -> bf16 round-to-nearest-even
__device__ __forceinline__ unsigned short f2bf(float f){
  unsigned u = __float_as_uint(f);
  unsigned r = u + 0x7FFFu + ((u >> 16) & 1u);
  return (unsigned short)(r >> 16);
}
__device__ __forceinline__ unsigned pack2(float a, float b){
  return (unsigned)f2bf(a) | ((unsigned)f2bf(b) << 16);
}
__device__ __forceinline__ float dot2bf(unsigned wpair, unsigned hpair, float acc){
  return __builtin_amdgcn_fdot2_f32_bf16(__builtin_bit_cast(bf2_t, wpair),
                                         __builtin_bit_cast(bf2_t, hpair), acc, false);
}
__device__ __forceinline__ void lds_barrier(){
  asm volatile("s_waitcnt lgkmcnt(0)\ns_barrier" ::: "memory");
}

// Per-row symmetric int8 quantization into MFMA B-fragment order for
// mfma_i32_16x16x64_i8 (W^T). Tile (s, g', w) covers rows i = 16w..16w+15 of
// gate g'; half m covers k = 64m..64m+63.
// uint4 idx = ((s*24 + g'*8 + w)*2 + m)*64 + q*16 + c holds int8 of
//   W_g'[s][i = 16w + c][k = m*64 + q*16 + e]  (byte e of word e>>2)
// A-side (h) uses the same (quad,byte)<->k convention -> any HW k-permutation
// cancels. scales[s*384 + g'*128 + i] = rowmax / (127*127)
__global__ __launch_bounds__(256) void pack_weights_i8(const float* __restrict__ Wr,
                                                       const float* __restrict__ Wz,
                                                       const float* __restrict__ Wn,
                                                       uint4* __restrict__ dst,
                                                       float* __restrict__ scales){
  int idx = blockIdx.x * 256 + threadIdx.x;     // (s, row384)
  if (idx >= NSW * 384) return;
  int s   = idx / 384;
  int row = idx % 384;
  int gp  = row >> 7;                            // gate 0..2
  int i   = row & 127;                           // output row within gate
  const float* W = (gp == 0) ? Wr : (gp == 1) ? Wz : Wn;
  const float* src = W + (size_t)s * (H_*H_) + (size_t)i * H_;
  float amax = 0.f;
  for (int j = 0; j < H_; ++j) amax = fmaxf(amax, fabsf(src[j]));
  amax = fmaxf(amax, 1e-20f);
  float inv = 127.f / amax;
  scales[idx] = amax / 16129.f;                 // amax / 127^2
  int w = i >> 4, c = i & 15;
  for (int m = 0; m < 2; ++m){
    for (int q = 0; q < 4; ++q){
      unsigned bw[4] = {0, 0, 0, 0};
      for (int e = 0; e < 16; ++e){
        int k = m * 64 + q * 16 + e;
        int v = (int)rintf(src[k] * inv);
        v = v > 127 ? 127 : (v < -127 ? -127 : v);
        bw[e >> 2] |= ((unsigned)(v & 0xFF)) << (8 * (e & 3));
      }
      dst[((size_t)((s * 24 + gp * 8 + w) * 2 + m)) * 64 + q * 16 + c] =
        make_uint4(bw[0], bw[1], bw[2], bw[3]);
    }
  }
}

// 512 threads = 8 waves. Transposed MFMA: A = h (row 0 only), B = W^T.
// Round-9 deltas (fix round-8 scratch spill, keep its wins):
//  - scale/b_n back in LDS but as ONE f32x4 array s_scl4[s][hi] =
//    {scl_r, scl_z, scl_n, b_hn} at 16-B stride: conflict-free b128, one
//    read/step, no arch-VGPR pressure (round-8's scb[6] registers spilled:
//    WRITE_SIZE 1->13 MB).
//  - r/z biases stay folded into x-tilde at the boundary.
//  - h-frag reads exec-masked to colv lanes; non-colv A-rows are register
//    zeros (no LDS pad reads); x-tilde read masked to L<16.
//  - MFMA k-halves independent (a.x + c.x).
__global__ __launch_bounds__(512, 2) void gru_run(const float* __restrict__ stim,
    const int*   __restrict__ swid,  const float* __restrict__ mask,
    const float* __restrict__ Win,   const float* __restrict__ binp,
    const float* __restrict__ b_hr,  const float* __restrict__ b_hz, const float* __restrict__ b_hn,
    const float* __restrict__ Wo,    const float* __restrict__ bo,
    const uint4* __restrict__ Wpk,   const float* __restrict__ Wsc,
    float* __restrict__ out)
{
  const int b   = blockIdx.x;
  const int tid = threadIdx.x;
  const int w   = tid >> 6;          // 0..7
  const int L   = tid & 63;

  __shared__ uint4          s_stim2[T_];            // 8 KB   bf16 stim pairs
  __shared__ unsigned       s_sm[T_];               // 2 KB   {bf16 mask <<16 | sid}
  __shared__ __align__(16) float2 s_brz[NSW][H_];     // 6 KB   {b_hr, b_hz} per (s,row)
  __shared__ __align__(16) f32x4  s_scl4[NSW][H_];    // 12 KB  {scl_r,scl_z,scl_n,b_hn}
  __shared__ __align__(16) f32x4  s_xt[32][H_];       // 64 KB  x-projection chunk (bias-folded)
  __shared__ __align__(16) float2 s_po[32][130];      // 32.5 KB output partials (padded)
  __shared__ __align__(16) char   s_hb8[2][H_];       // linear int8 h slots

  // ---- init LDS ----
  for (int k = tid; k < T_; k += 512){
    const float* sp = stim + (size_t)b * T_ * 8 + (size_t)k * 8;
    uint4 o;
    o.x = pack2(sp[0], sp[1]); o.y = pack2(sp[2], sp[3]);
    o.z = pack2(sp[4], sp[5]); o.w = pack2(sp[6], sp[7]);
    s_stim2[k] = o;
    int ss = swid[(size_t)b * T_ + k];
    ss = ss < 0 ? 0 : (ss > NSW - 1 ? NSW - 1 : ss);
    s_sm[k] = ((unsigned)f2bf(mask[(size_t)b * T_ + k]) << 16) | (unsigned)ss;
  }
  for (int k = tid; k < NSW * H_; k += 512){
    int s = k >> 7, i = k & 127;
    s_brz[s][i]  = make_float2(b_hr[s * H_ + i], b_hz[s * H_ + i]);
    s_scl4[s][i] = (f32x4){Wsc[s * 384 + i], Wsc[s * 384 + 128 + i],
                           Wsc[s * 384 + 256 + i], b_hn[s * H_ + i]};
  }
  if (tid < 64) ((int*)s_hb8)[tid] = 0;          // zero both int8 slots

  // pre-phase x-projection weights: thread handles row hi_p for all 3 gates
  const int hi_p = tid & 127;
  const int tq   = tid >> 7;                     // 0..3: covers t-offsets tq*8..tq*8+7
  unsigned winp[3][4];
  float    binr[3];
  #pragma unroll
  for (int gp = 0; gp < 3; ++gp){
    int row = gp * 128 + hi_p;
    #pragma unroll
    for (int e = 0; e < 4; ++e)
      winp[gp][e] = pack2(Win[(size_t)row * 8 + 2*e], Win[(size_t)row * 8 + 2*e + 1]);
    binr[gp] = binp[row];
  }

  const bool colv = (L & 15) == 0;
  const int  quad = L >> 4;
  const int  hi_  = 16 * w + (L & 15);
  float* outp = out + (size_t)b * T_ * 2;
  const float bo0 = bo[0], bo1 = bo[1];
  float wo0r = 0.f, wo1r = 0.f;
  if (L < 16){ wo0r = Wo[hi_]; wo1r = Wo[H_ + hi_]; }

  // ---- preload ALL 6 switch-sets' B fragments (W^T). volatile: cannot be
  //      sunk into the loop or rematerialized. 6 x 6 x uint4 = 144 regs (AGPR).
  uint4 Bf[6][6];
  #pragma unroll
  for (int s = 0; s < 6; ++s){
    #pragma unroll
    for (int gp = 0; gp < 3; ++gp){
      #pragma unroll
      for (int m = 0; m < 2; ++m){
        const volatile unsigned* vp =
          (const volatile unsigned*)(Wpk + ((size_t)((s * 24 + gp * 8 + w) * 2 + m)) * 64 + L);
        Bf[s][gp*2+m].x = vp[0];
        Bf[s][gp*2+m].y = vp[1];
        Bf[s][gp*2+m].z = vp[2];
        Bf[s][gp*2+m].w = vp[3];
      }
    }
  }

  __syncthreads();

  float hprev = 0.f;
  int   smv = 0;                                 // 64 steps of {mask|sid}, lane L = step

#define MFMA64(A_, B_, C_) __builtin_amdgcn_mfma_i32_16x16x64_i8( \
    __builtin_bit_cast(i32x4, (A_)), __builtin_bit_cast(i32x4, (B_)), (C_), 0, 0, 0)
#define MM(S)                                                                  \
    { i32x4 a, c; const i32x4 zz = {0,0,0,0};                                  \
      a = MFMA64(blo, Bf[S][0], zz); c = MFMA64(bhi, Bf[S][1], zz);            \
      acx0 = a.x + c.x;                                                        \
      a = MFMA64(blo, Bf[S][2], zz); c = MFMA64(bhi, Bf[S][3], zz);            \
      acx1 = a.x + c.x;                                                        \
      a = MFMA64(blo, Bf[S][4], zz); c = MFMA64(bhi, Bf[S][5], zz);            \
      acx2 = a.x + c.x; }

#define REDUCE(TBASE)                                                          \
  {                                                                            \
    int tp = tid >> 4;                                                         \
    int q  = tid & 15;                                                         \
    const f32x4* prow = (const f32x4*)&s_po[tp][0];                            \
    f32x4 a0 = prow[q], a1 = prow[q+16], a2 = prow[q+32], a3 = prow[q+48];     \
    f32x4 sv = (a0 + a1) + (a2 + a3);                                          \
    float p0 = sv.x + sv.z, p1 = sv.y + sv.w;                                  \
    p0 += __shfl_down(p0, 8, 16); p1 += __shfl_down(p1, 8, 16);                \
    p0 += __shfl_down(p0, 4, 16); p1 += __shfl_down(p1, 4, 16);                \
    p0 += __shfl_down(p0, 2, 16); p1 += __shfl_down(p1, 2, 16);                \
    p0 += __shfl_down(p0, 1, 16); p1 += __shfl_down(p1, 1, 16);                \
    if (q == 0)                                                                \
      *(float2*)&outp[((TBASE) + tp) * 2] = make_float2(p0 + bo0, p1 + bo1);   \
  }

  #pragma unroll 1
  for (int t = 0; t < T_; ++t){
    // ---- chunk boundary: reduce previous chunk's outputs + build x̃ chunk ----
    if ((t & 31) == 0){
      if (t > 0) REDUCE(t - 32);
      #pragma unroll
      for (int j = 0; j < 8; ++j){
        int tt = t + tq * 8 + j;
        uint4 sp = s_stim2[tt];
        int sid_tt = (int)(s_sm[tt] & 0xFFFFu);        // wave-uniform
        float2 brz = s_brz[sid_tt][hi_p];
        float x0 = binr[0];
        x0 = dot2bf(winp[0][0], sp.x, x0); x0 = dot2bf(winp[0][1], sp.y, x0);
        x0 = dot2bf(winp[0][2], sp.z, x0); x0 = dot2bf(winp[0][3], sp.w, x0);
        float x1 = binr[1];
        x1 = dot2bf(winp[1][0], sp.x, x1); x1 = dot2bf(winp[1][1], sp.y, x1);
        x1 = dot2bf(winp[1][2], sp.z, x1); x1 = dot2bf(winp[1][3], sp.w, x1);
        float x2 = binr[2];
        x2 = dot2bf(winp[2][0], sp.x, x2); x2 = dot2bf(winp[2][1], sp.y, x2);
        x2 = dot2bf(winp[2][2], sp.z, x2); x2 = dot2bf(winp[2][3], sp.w, x2);
        f32x4 xv;
        xv.x = x0 + brz.x;          // r-gate bias folded
        xv.y = x1 + brz.y;          // z-gate bias folded
        xv.z = x2;                  // b_n NOT foldable (sits inside r * (...))
        xv.w = 0.f;
        s_xt[tq * 8 + j][hi_p] = xv;
      }
      lds_barrier();
    }
    if ((t & 63) == 0) smv = (int)s_sm[t + L];   // 64 steps of {mask|sid} into a VGPR

    // per-step uniform sid/mask via readlane (zero DS)
    int   sm_c = __builtin_amdgcn_readlane(smv, t & 63);
    int   sc   = sm_c & 0xFFFF;
    float mt   = __uint_as_float((unsigned)sm_c & 0xFFFF0000u);

    // per-lane {scl_r,scl_z,scl_n,b_hn}: one conflict-free b128, issued early
    f32x4 sclv = {0.f, 0.f, 0.f, 0.f};
    if (L < 16) sclv = s_scl4[sc][hi_];

    // A fragments: h_{t-1} linear int8; exec-masked to the 4 colv lanes,
    // non-colv lanes (A rows 1..15) are register zeros
    const char* hsrc = &s_hb8[(t + 1) & 1][0];
    uint4 blo = {0, 0, 0, 0}, bhi = {0, 0, 0, 0};
    if (colv){
      blo = *(const uint4*)(hsrc + quad * 16);
      bhi = *(const uint4*)(hsrc + 64 + quad * 16);
    }

    // x̃ for this lane's row (only L<16 uses it; masked read)
    f32x4 xtv = {0.f, 0.f, 0.f, 0.f};
    if (L < 16) xtv = s_xt[t & 31][hi_];

    // matvec: C[0][n] lands in lanes 0..15, reg .x  (A rows 1..15 are zero)
    int acx0, acx1, acx2;
    switch (sc){
      case 0: MM(0); break;
      case 1: MM(1); break;
      case 2: MM(2); break;
      case 3: MM(3); break;
      case 4: MM(4); break;
      default: MM(5); break;
    }

    // dequant + pointwise, fully in-register (lane l<16: h row 16w+l)
    if (L < 16){
      float ar = fmaf((float)acx0, sclv.x, xtv.x);      // includes x + b_r
      float az = fmaf((float)acx1, sclv.y, xtv.y);      // includes x + b_z
      float an = fmaf((float)acx2, sclv.z, sclv.w);     // matvec*scl + b_n
      float r = __builtin_amdgcn_rcpf(1.f + __expf(-ar));
      float z = __builtin_amdgcn_rcpf(1.f + __expf(-az));
      float e = __expf(2.f * fmaf(r, an, xtv.z));       // tanh(a) = 1 - 2/(e^{2a}+1)
      float n = fmaf(-2.f, __builtin_amdgcn_rcpf(e + 1.f), 1.f);
      float hnew = fmaf(z, hprev - n, n);
      float ho   = fmaf(mt, hnew - hprev, hprev);
      hprev = ho;
      float qf = fminf(fmaxf(ho * 127.f, -127.f), 127.f);
      s_hb8[t & 1][hi_] = (char)(int)rintf(qf);          // h byte first (consumers wait on it)
      s_po[t & 31][hi_] = make_float2(wo0r * ho, wo1r * ho);
    }

    lds_barrier();   // the ONLY barrier: h_t visible (and boundary data stable)
  }

  // final chunk's outputs
  REDUCE(T_ - 32);
#undef REDUCE
#undef MM
#undef MFMA64
}

extern "C" void kernel_launch(void* const* d_in, const int* in_sizes, int n_in,
                              void* d_out, int out_size, void* d_ws, size_t ws_size,
                              hipStream_t stream) {
  const float* stim = (const float*)d_in[0];
  const int*   swid = (const int*)  d_in[1];
  const float* mask = (const float*)d_in[2];
  const float* Win  = (const float*)d_in[3];
  const float* binp = (const float*)d_in[4];
  const float* Whr  = (const float*)d_in[5];
  const float* Whz  = (const float*)d_in[6];
  const float* Whn  = (const float*)d_in[7];
  const float* bhr  = (const float*)d_in[8];
  const float* bhz  = (const float*)d_in[9];
  const float* bhn  = (const float*)d_in[10];
  const float* Wo   = (const float*)d_in[11];
  const float* bo   = (const float*)d_in[12];

  uint4* wpk = (uint4*)d_ws;                       // 294912 B packed int8 frags
  float* wsc = (float*)((char*)d_ws + 294912);     // 9216 B row scales

  pack_weights_i8<<<9, 256, 0, stream>>>(Whr, Whz, Whn, wpk, wsc);
  gru_run<<<B_, 512, 0, stream>>>(stim, swid, mask, Win, binp,
                                  bhr, bhz, bhn, Wo, bo, wpk, wsc, (float*)d_out);
}

// Round 10
// 348.810 us; speedup vs baseline: 1.1533x; 1.0833x over previous
//
#include <hip/hip_runtime.h>
#include <stdint.h>

#define B_  256
#define T_  512
#define H_  128
#define NSW 6

typedef __bf16 bf2_t  __attribute__((ext_vector_type(2)));
typedef int    i32x4  __attribute__((ext_vector_type(4)));
typedef float  f32x4  __attribute__((ext_vector_type(4)));

// float -> bf16 round-to-nearest-even
__device__ __forceinline__ unsigned short f2bf(float f){
  unsigned u = __float_as_uint(f);
  unsigned r = u + 0x7FFFu + ((u >> 16) & 1u);
  return (unsigned short)(r >> 16);
}
__device__ __forceinline__ unsigned pack2(float a, float b){
  return (unsigned)f2bf(a) | ((unsigned)f2bf(b) << 16);
}
__device__ __forceinline__ float dot2bf(unsigned wpair, unsigned hpair, float acc){
  return __builtin_amdgcn_fdot2_f32_bf16(__builtin_bit_cast(bf2_t, wpair),
                                         __builtin_bit_cast(bf2_t, hpair), acc, false);
}
__device__ __forceinline__ void lds_barrier(){
  asm volatile("s_waitcnt lgkmcnt(0)\ns_barrier" ::: "memory");
}

// Per-row symmetric int8 quantization into MFMA B-fragment order for
// mfma_i32_16x16x64_i8 (W^T). Tile (s, g', w) covers rows i = 16w..16w+15 of
// gate g'; half m covers k = 64m..64m+63.
// uint4 idx = ((s*24 + g'*8 + w)*2 + m)*64 + q*16 + c holds int8 of
//   W_g'[s][i = 16w + c][k = m*64 + q*16 + e]  (byte e of word e>>2)
// A-side (h) uses the same (quad,byte)<->k convention -> any HW k-permutation
// cancels. scales[s*384 + g'*128 + i] = rowmax / (127*127)
__global__ __launch_bounds__(256) void pack_weights_i8(const float* __restrict__ Wr,
                                                       const float* __restrict__ Wz,
                                                       const float* __restrict__ Wn,
                                                       uint4* __restrict__ dst,
                                                       float* __restrict__ scales){
  int idx = blockIdx.x * 256 + threadIdx.x;     // (s, row384)
  if (idx >= NSW * 384) return;
  int s   = idx / 384;
  int row = idx % 384;
  int gp  = row >> 7;                            // gate 0..2
  int i   = row & 127;                           // output row within gate
  const float* W = (gp == 0) ? Wr : (gp == 1) ? Wz : Wn;
  const float* src = W + (size_t)s * (H_*H_) + (size_t)i * H_;
  float amax = 0.f;
  for (int j = 0; j < H_; ++j) amax = fmaxf(amax, fabsf(src[j]));
  amax = fmaxf(amax, 1e-20f);
  float inv = 127.f / amax;
  scales[idx] = amax / 16129.f;                 // amax / 127^2
  int w = i >> 4, c = i & 15;
  for (int m = 0; m < 2; ++m){
    for (int q = 0; q < 4; ++q){
      unsigned bw[4] = {0, 0, 0, 0};
      for (int e = 0; e < 16; ++e){
        int k = m * 64 + q * 16 + e;
        int v = (int)rintf(src[k] * inv);
        v = v > 127 ? 127 : (v < -127 ? -127 : v);
        bw[e >> 2] |= ((unsigned)(v & 0xFF)) << (8 * (e & 3));
      }
      dst[((size_t)((s * 24 + gp * 8 + w) * 2 + m)) * 64 + q * 16 + c] =
        make_uint4(bw[0], bw[1], bw[2], bw[3]);
    }
  }
}

// 512 threads = 8 waves. Transposed MFMA: A = h (row 0 only), B = W^T.
// Round-10 deltas (VALU-issue + addressing cuts; structure unchanged):
//  - nested loops: outer 16 chunks of 32; inner unroll-2 so step parity,
//    h-slot selection and the per-step (t&31)/(t&63) checks are compile-time;
//    s_xt/s_po/s_hb8 addressing becomes constant-increment.
//  - blo/bhi/sclv/xtv are PERSISTENT registers, zero-initialized once;
//    exec-masked ds_reads update only active lanes (kills 16 v_mov/step).
//  - quant clamp dropped: |h| < 1 by induction ((1-z)n + z*h, |tanh|<1,
//    h0=0, mask in {0,1}) -> rintf(ho*127) always in [-127,127].
//  - h-frag reads issued FIRST after the barrier (MFMA waits drain less).
__global__ __launch_bounds__(512, 2) void gru_run(const float* __restrict__ stim,
    const int*   __restrict__ swid,  const float* __restrict__ mask,
    const float* __restrict__ Win,   const float* __restrict__ binp,
    const float* __restrict__ b_hr,  const float* __restrict__ b_hz, const float* __restrict__ b_hn,
    const float* __restrict__ Wo,    const float* __restrict__ bo,
    const uint4* __restrict__ Wpk,   const float* __restrict__ Wsc,
    float* __restrict__ out)
{
  const int b   = blockIdx.x;
  const int tid = threadIdx.x;
  const int w   = tid >> 6;          // 0..7
  const int L   = tid & 63;

  __shared__ uint4          s_stim2[T_];            // 8 KB   bf16 stim pairs
  __shared__ unsigned       s_sm[T_];               // 2 KB   {bf16 mask <<16 | sid}
  __shared__ __align__(16) float2 s_brz[NSW][H_];     // 6 KB   {b_hr, b_hz} per (s,row)
  __shared__ __align__(16) f32x4  s_scl4[NSW][H_];    // 12 KB  {scl_r,scl_z,scl_n,b_hn}
  __shared__ __align__(16) f32x4  s_xt[32][H_];       // 64 KB  x-projection chunk (bias-folded)
  __shared__ __align__(16) float2 s_po[32][130];      // 32.5 KB output partials (padded)
  __shared__ __align__(16) char   s_hb8[2][H_];       // linear int8 h slots

  // ---- init LDS ----
  for (int k = tid; k < T_; k += 512){
    const float* sp = stim + (size_t)b * T_ * 8 + (size_t)k * 8;
    uint4 o;
    o.x = pack2(sp[0], sp[1]); o.y = pack2(sp[2], sp[3]);
    o.z = pack2(sp[4], sp[5]); o.w = pack2(sp[6], sp[7]);
    s_stim2[k] = o;
    int ss = swid[(size_t)b * T_ + k];
    ss = ss < 0 ? 0 : (ss > NSW - 1 ? NSW - 1 : ss);
    s_sm[k] = ((unsigned)f2bf(mask[(size_t)b * T_ + k]) << 16) | (unsigned)ss;
  }
  for (int k = tid; k < NSW * H_; k += 512){
    int s = k >> 7, i = k & 127;
    s_brz[s][i]  = make_float2(b_hr[s * H_ + i], b_hz[s * H_ + i]);
    s_scl4[s][i] = (f32x4){Wsc[s * 384 + i], Wsc[s * 384 + 128 + i],
                           Wsc[s * 384 + 256 + i], b_hn[s * H_ + i]};
  }
  if (tid < 64) ((int*)s_hb8)[tid] = 0;          // zero both int8 slots

  // pre-phase x-projection weights: thread handles row hi_p for all 3 gates
  const int hi_p = tid & 127;
  const int tq   = tid >> 7;                     // 0..3: covers t-offsets tq*8..tq*8+7
  unsigned winp[3][4];
  float    binr[3];
  #pragma unroll
  for (int gp = 0; gp < 3; ++gp){
    int row = gp * 128 + hi_p;
    #pragma unroll
    for (int e = 0; e < 4; ++e)
      winp[gp][e] = pack2(Win[(size_t)row * 8 + 2*e], Win[(size_t)row * 8 + 2*e + 1]);
    binr[gp] = binp[row];
  }

  const bool colv = (L & 15) == 0;
  const int  quad = L >> 4;
  const int  hi_  = 16 * w + (L & 15);
  float* outp = out + (size_t)b * T_ * 2;
  const float bo0 = bo[0], bo1 = bo[1];
  float wo0r = 0.f, wo1r = 0.f;
  if (L < 16){ wo0r = Wo[hi_]; wo1r = Wo[H_ + hi_]; }

  // ---- preload ALL 6 switch-sets' B fragments (W^T). volatile: cannot be
  //      sunk into the loop or rematerialized. 6 x 6 x uint4 = 144 regs (AGPR).
  uint4 Bf[6][6];
  #pragma unroll
  for (int s = 0; s < 6; ++s){
    #pragma unroll
    for (int gp = 0; gp < 3; ++gp){
      #pragma unroll
      for (int m = 0; m < 2; ++m){
        const volatile unsigned* vp =
          (const volatile unsigned*)(Wpk + ((size_t)((s * 24 + gp * 8 + w) * 2 + m)) * 64 + L);
        Bf[s][gp*2+m].x = vp[0];
        Bf[s][gp*2+m].y = vp[1];
        Bf[s][gp*2+m].z = vp[2];
        Bf[s][gp*2+m].w = vp[3];
      }
    }
  }

  __syncthreads();

  float hprev = 0.f;
  int   smv = 0;                       // 64 steps of {mask|sid}, lane L = step
  // persistent exec-masked registers: zeros written ONCE; masked reads below
  // update only the active lanes, so inactive lanes keep zero forever.
  uint4 blo = {0, 0, 0, 0}, bhi = {0, 0, 0, 0};
  f32x4 sclv = {0.f, 0.f, 0.f, 0.f}, xtv = {0.f, 0.f, 0.f, 0.f};

#define MFMA64(A_, B_, C_) __builtin_amdgcn_mfma_i32_16x16x64_i8( \
    __builtin_bit_cast(i32x4, (A_)), __builtin_bit_cast(i32x4, (B_)), (C_), 0, 0, 0)
#define MM(S)                                                                  \
    { i32x4 a, c; const i32x4 zz = {0,0,0,0};                                  \
      a = MFMA64(blo, Bf[S][0], zz); c = MFMA64(bhi, Bf[S][1], zz);            \
      acx0 = a.x + c.x;                                                        \
      a = MFMA64(blo, Bf[S][2], zz); c = MFMA64(bhi, Bf[S][3], zz);            \
      acx1 = a.x + c.x;                                                        \
      a = MFMA64(blo, Bf[S][4], zz); c = MFMA64(bhi, Bf[S][5], zz);            \
      acx2 = a.x + c.x; }

#define REDUCE(TBASE)                                                          \
  {                                                                            \
    int tp = tid >> 4;                                                         \
    int q  = tid & 15;                                                         \
    const f32x4* prow = (const f32x4*)&s_po[tp][0];                            \
    f32x4 a0 = prow[q], a1 = prow[q+16], a2 = prow[q+32], a3 = prow[q+48];     \
    f32x4 sv = (a0 + a1) + (a2 + a3);                                          \
    float p0 = sv.x + sv.z, p1 = sv.y + sv.w;                                  \
    p0 += __shfl_down(p0, 8, 16); p1 += __shfl_down(p1, 8, 16);                \
    p0 += __shfl_down(p0, 4, 16); p1 += __shfl_down(p1, 4, 16);                \
    p0 += __shfl_down(p0, 2, 16); p1 += __shfl_down(p1, 2, 16);                \
    p0 += __shfl_down(p0, 1, 16); p1 += __shfl_down(p1, 1, 16);                \
    if (q == 0)                                                                \
      *(float2*)&outp[((TBASE) + tp) * 2] = make_float2(p0 + bo0, p1 + bo1);   \
  }

  #pragma unroll 1
  for (int ch = 0; ch < 16; ++ch){
    const int t0 = ch << 5;

    // ---- chunk boundary: reduce previous chunk's outputs + build x̃ chunk ----
    if (ch > 0) REDUCE(t0 - 32);
    #pragma unroll
    for (int j = 0; j < 8; ++j){
      int tt = t0 + tq * 8 + j;
      uint4 sp = s_stim2[tt];
      int sid_tt = (int)(s_sm[tt] & 0xFFFFu);        // wave-uniform
      float2 brz = s_brz[sid_tt][hi_p];
      float x0 = binr[0];
      x0 = dot2bf(winp[0][0], sp.x, x0); x0 = dot2bf(winp[0][1], sp.y, x0);
      x0 = dot2bf(winp[0][2], sp.z, x0); x0 = dot2bf(winp[0][3], sp.w, x0);
      float x1 = binr[1];
      x1 = dot2bf(winp[1][0], sp.x, x1); x1 = dot2bf(winp[1][1], sp.y, x1);
      x1 = dot2bf(winp[1][2], sp.z, x1); x1 = dot2bf(winp[1][3], sp.w, x1);
      float x2 = binr[2];
      x2 = dot2bf(winp[2][0], sp.x, x2); x2 = dot2bf(winp[2][1], sp.y, x2);
      x2 = dot2bf(winp[2][2], sp.z, x2); x2 = dot2bf(winp[2][3], sp.w, x2);
      f32x4 xv;
      xv.x = x0 + brz.x;          // r-gate bias folded
      xv.y = x1 + brz.y;          // z-gate bias folded
      xv.z = x2;                  // b_n NOT foldable (sits inside r * (...))
      xv.w = 0.f;
      s_xt[tq * 8 + j][hi_p] = xv;
    }
    lds_barrier();                 // x̃ chunk + REDUCE order vs step writes

    if ((ch & 1) == 0) smv = (int)s_sm[t0 + L];   // 64 steps of {mask|sid}
    const int tb = (ch & 1) << 5;

    #pragma unroll 2
    for (int u = 0; u < 32; ++u){
      // A fragments first (MFMA's wait drains less): h_{t-1} in slot (u+1)&1,
      // exec-masked to the 4 colv lanes; other lanes keep persistent zeros.
      const char* hsrc = &s_hb8[(u + 1) & 1][0];
      if (colv){
        blo = *(const uint4*)(hsrc + quad * 16);
        bhi = *(const uint4*)(hsrc + 64 + quad * 16);
      }
      // x̃ (t-dependent only) issued early too
      if (L < 16) xtv = s_xt[u][hi_];

      // per-step uniform sid/mask via readlane (zero DS)
      int   sm_c = __builtin_amdgcn_readlane(smv, tb + u);
      int   sc   = sm_c & 0xFFFF;
      float mt   = __uint_as_float((unsigned)sm_c & 0xFFFF0000u);

      // per-lane {scl_r,scl_z,scl_n,b_hn}: one conflict-free b128
      if (L < 16) sclv = s_scl4[sc][hi_];

      // matvec: C[0][n] lands in lanes 0..15, reg .x  (A rows 1..15 are zero)
      int acx0, acx1, acx2;
      switch (sc){
        case 0: MM(0); break;
        case 1: MM(1); break;
        case 2: MM(2); break;
        case 3: MM(3); break;
        case 4: MM(4); break;
        default: MM(5); break;
      }

      // dequant + pointwise, fully in-register (lane l<16: h row 16w+l)
      if (L < 16){
        float ar = fmaf((float)acx0, sclv.x, xtv.x);      // includes x + b_r
        float az = fmaf((float)acx1, sclv.y, xtv.y);      // includes x + b_z
        float an = fmaf((float)acx2, sclv.z, sclv.w);     // matvec*scl + b_n
        float r = __builtin_amdgcn_rcpf(1.f + __expf(-ar));
        float z = __builtin_amdgcn_rcpf(1.f + __expf(-az));
        float e = __expf(2.f * fmaf(r, an, xtv.z));       // tanh(a) = 1 - 2/(e^{2a}+1)
        float n = fmaf(-2.f, __builtin_amdgcn_rcpf(e + 1.f), 1.f);
        float hnew = fmaf(z, hprev - n, n);
        float ho   = fmaf(mt, hnew - hprev, hprev);
        hprev = ho;
        // no clamp: |h| < 1 by induction -> rint(ho*127) in [-127,127]
        s_hb8[u & 1][hi_] = (char)(int)rintf(ho * 127.f);  // h first (consumers wait on it)
        s_po[u][hi_] = make_float2(wo0r * ho, wo1r * ho);
      }

      lds_barrier();   // the ONLY per-step barrier: h_t visible
    }
  }

  // final chunk's outputs
  REDUCE(T_ - 32);
#undef REDUCE
#undef MM
#undef MFMA64
}

extern "C" void kernel_launch(void* const* d_in, const int* in_sizes, int n_in,
                              void* d_out, int out_size, void* d_ws, size_t ws_size,
                              hipStream_t stream) {
  const float* stim = (const float*)d_in[0];
  const int*   swid = (const int*)  d_in[1];
  const float* mask = (const float*)d_in[2];
  const float* Win  = (const float*)d_in[3];
  const float* binp = (const float*)d_in[4];
  const float* Whr  = (const float*)d_in[5];
  const float* Whz  = (const float*)d_in[6];
  const float* Whn  = (const float*)d_in[7];
  const float* bhr  = (const float*)d_in[8];
  const float* bhz  = (const float*)d_in[9];
  const float* bhn  = (const float*)d_in[10];
  const float* Wo   = (const float*)d_in[11];
  const float* bo   = (const float*)d_in[12];

  uint4* wpk = (uint4*)d_ws;                       // 294912 B packed int8 frags
  float* wsc = (float*)((char*)d_ws + 294912);     // 9216 B row scales

  pack_weights_i8<<<9, 256, 0, stream>>>(Whr, Whz, Whn, wpk, wsc);
  gru_run<<<B_, 512, 0, stream>>>(stim, swid, mask, Win, binp,
                                  bhr, bhz, bhn, Wo, bo, wpk, wsc, (float*)d_out);
}

// Round 11
// 335.907 us; speedup vs baseline: 1.1976x; 1.0384x over previous
//
#include <hip/hip_runtime.h>
#include <stdint.h>

#define B_  256
#define T_  512
#define H_  128
#define NSW 6

typedef __bf16 bf2_t  __attribute__((ext_vector_type(2)));
typedef int    i32x4  __attribute__((ext_vector_type(4)));
typedef float  f32x4  __attribute__((ext_vector_type(4)));

// float -> bf16 round-to-nearest-even
__device__ __forceinline__ unsigned short f2bf(float f){
  unsigned u = __float_as_uint(f);
  unsigned r = u + 0x7FFFu + ((u >> 16) & 1u);
  return (unsigned short)(r >> 16);
}
__device__ __forceinline__ unsigned pack2(float a, float b){
  return (unsigned)f2bf(a) | ((unsigned)f2bf(b) << 16);
}
__device__ __forceinline__ float dot2bf(unsigned wpair, unsigned hpair, float acc){
  return __builtin_amdgcn_fdot2_f32_bf16(__builtin_bit_cast(bf2_t, wpair),
                                         __builtin_bit_cast(bf2_t, hpair), acc, false);
}
__device__ __forceinline__ void lds_barrier(){
  asm volatile("s_waitcnt lgkmcnt(0)\ns_barrier" ::: "memory");
}

// Per-row symmetric int8 quantization into MFMA B-fragment order for
// mfma_i32_16x16x64_i8 (W^T). Tile (s, g', w) covers rows i = 16w..16w+15 of
// gate g'; half m covers k = 64m..64m+63.
// uint4 idx = ((s*24 + g'*8 + w)*2 + m)*64 + q*16 + c holds int8 of
//   W_g'[s][i = 16w + c][k = m*64 + q*16 + e]  (byte e of word e>>2)
// A-side (h) uses the same (quad,byte)<->k convention -> any HW k-permutation
// cancels. scales[s*384 + g'*128 + i] = rowmax / (127*127)
__global__ __launch_bounds__(256) void pack_weights_i8(const float* __restrict__ Wr,
                                                       const float* __restrict__ Wz,
                                                       const float* __restrict__ Wn,
                                                       uint4* __restrict__ dst,
                                                       float* __restrict__ scales){
  int idx = blockIdx.x * 256 + threadIdx.x;     // (s, row384)
  if (idx >= NSW * 384) return;
  int s   = idx / 384;
  int row = idx % 384;
  int gp  = row >> 7;                            // gate 0..2
  int i   = row & 127;                           // output row within gate
  const float* W = (gp == 0) ? Wr : (gp == 1) ? Wz : Wn;
  const float* src = W + (size_t)s * (H_*H_) + (size_t)i * H_;
  float amax = 0.f;
  for (int j = 0; j < H_; ++j) amax = fmaxf(amax, fabsf(src[j]));
  amax = fmaxf(amax, 1e-20f);
  float inv = 127.f / amax;
  scales[idx] = amax / 16129.f;                 // amax / 127^2
  int w = i >> 4, c = i & 15;
  for (int m = 0; m < 2; ++m){
    for (int q = 0; q < 4; ++q){
      unsigned bw[4] = {0, 0, 0, 0};
      for (int e = 0; e < 16; ++e){
        int k = m * 64 + q * 16 + e;
        int v = (int)rintf(src[k] * inv);
        v = v > 127 ? 127 : (v < -127 ? -127 : v);
        bw[e >> 2] |= ((unsigned)(v & 0xFF)) << (8 * (e & 3));
      }
      dst[((size_t)((s * 24 + gp * 8 + w) * 2 + m)) * 64 + q * 16 + c] =
        make_uint4(bw[0], bw[1], bw[2], bw[3]);
    }
  }
}

// 512 threads = 8 waves. Transposed MFMA: A = h (row 0 only), B = W^T.
// Round-11 deltas (empty the post-barrier critical section):
//  - operand ROTATION: sid/mask (readlane), xtv and sclv for step u+1 are
//    h-independent -> prefetched during step u (issued right after the h-frag
//    reads, latency hides under MFMA+pointwise), A/B double-buffered with
//    compile-time parity. Post-barrier path = h-read -> MFMA (branch already
//    resolved) -> pointwise -> writes -> barrier.
//  - inner loop: 3 x unroll-8 + fully-unrolled 8-step tail -> ds addressing
//    collapses to base+immediate offsets; smv reloaded per 32-step chunk.
//  - winp/binr scoped INTO the boundary block (reloaded from L2-resident
//    Win/binp each chunk) -> 15 persistent arch VGPRs freed, protecting the
//    256-reg unified cap (144 AGPR weight payload) from a round-8-style spill.
__global__ __launch_bounds__(512, 2) void gru_run(const float* __restrict__ stim,
    const int*   __restrict__ swid,  const float* __restrict__ mask,
    const float* __restrict__ Win,   const float* __restrict__ binp,
    const float* __restrict__ b_hr,  const float* __restrict__ b_hz, const float* __restrict__ b_hn,
    const float* __restrict__ Wo,    const float* __restrict__ bo,
    const uint4* __restrict__ Wpk,   const float* __restrict__ Wsc,
    float* __restrict__ out)
{
  const int b   = blockIdx.x;
  const int tid = threadIdx.x;
  const int w   = tid >> 6;          // 0..7
  const int L   = tid & 63;

  __shared__ uint4          s_stim2[T_];            // 8 KB   bf16 stim pairs
  __shared__ unsigned       s_sm[T_];               // 2 KB   {bf16 mask <<16 | sid}
  __shared__ __align__(16) float2 s_brz[NSW][H_];     // 6 KB   {b_hr, b_hz} per (s,row)
  __shared__ __align__(16) f32x4  s_scl4[NSW][H_];    // 12 KB  {scl_r,scl_z,scl_n,b_hn}
  __shared__ __align__(16) f32x4  s_xt[32][H_];       // 64 KB  x-projection chunk (bias-folded)
  __shared__ __align__(16) float2 s_po[32][130];      // 32.5 KB output partials (padded)
  __shared__ __align__(16) char   s_hb8[2][H_];       // linear int8 h slots

  // ---- init LDS ----
  for (int k = tid; k < T_; k += 512){
    const float* sp = stim + (size_t)b * T_ * 8 + (size_t)k * 8;
    uint4 o;
    o.x = pack2(sp[0], sp[1]); o.y = pack2(sp[2], sp[3]);
    o.z = pack2(sp[4], sp[5]); o.w = pack2(sp[6], sp[7]);
    s_stim2[k] = o;
    int ss = swid[(size_t)b * T_ + k];
    ss = ss < 0 ? 0 : (ss > NSW - 1 ? NSW - 1 : ss);
    s_sm[k] = ((unsigned)f2bf(mask[(size_t)b * T_ + k]) << 16) | (unsigned)ss;
  }
  for (int k = tid; k < NSW * H_; k += 512){
    int s = k >> 7, i = k & 127;
    s_brz[s][i]  = make_float2(b_hr[s * H_ + i], b_hz[s * H_ + i]);
    s_scl4[s][i] = (f32x4){Wsc[s * 384 + i], Wsc[s * 384 + 128 + i],
                           Wsc[s * 384 + 256 + i], b_hn[s * H_ + i]};
  }
  if (tid < 64) ((int*)s_hb8)[tid] = 0;          // zero both int8 slots

  const int hi_p = tid & 127;
  const int tq   = tid >> 7;                     // 0..3: covers t-offsets tq*8..tq*8+7

  const bool colv = (L & 15) == 0;
  const int  quad = L >> 4;
  const int  hi_  = 16 * w + (L & 15);
  float* outp = out + (size_t)b * T_ * 2;
  const float bo0 = bo[0], bo1 = bo[1];
  float wo0r = 0.f, wo1r = 0.f;
  if (L < 16){ wo0r = Wo[hi_]; wo1r = Wo[H_ + hi_]; }

  // ---- preload ALL 6 switch-sets' B fragments (W^T). volatile: cannot be
  //      sunk into the loop or rematerialized. 6 x 6 x uint4 = 144 regs (AGPR).
  uint4 Bf[6][6];
  #pragma unroll
  for (int s = 0; s < 6; ++s){
    #pragma unroll
    for (int gp = 0; gp < 3; ++gp){
      #pragma unroll
      for (int m = 0; m < 2; ++m){
        const volatile unsigned* vp =
          (const volatile unsigned*)(Wpk + ((size_t)((s * 24 + gp * 8 + w) * 2 + m)) * 64 + L);
        Bf[s][gp*2+m].x = vp[0];
        Bf[s][gp*2+m].y = vp[1];
        Bf[s][gp*2+m].z = vp[2];
        Bf[s][gp*2+m].w = vp[3];
      }
    }
  }

  __syncthreads();

  float hprev = 0.f;
  int   smv = 0;                       // 32 steps of {mask|sid}, lane (L&31) = step
  // persistent rotated operand sets (A = even steps, B = odd steps) and
  // persistent exec-masked registers (zeros written once).
  uint4 blo = {0, 0, 0, 0}, bhi = {0, 0, 0, 0};
  f32x4 xtvA = {0.f,0.f,0.f,0.f}, xtvB = {0.f,0.f,0.f,0.f};
  f32x4 sclvA = {0.f,0.f,0.f,0.f}, sclvB = {0.f,0.f,0.f,0.f};
  float mtA = 0.f, mtB = 0.f;
  int   scA = 0,  scB = 0;

#define MFMA64(A_, B_, C_) __builtin_amdgcn_mfma_i32_16x16x64_i8( \
    __builtin_bit_cast(i32x4, (A_)), __builtin_bit_cast(i32x4, (B_)), (C_), 0, 0, 0)
#define MM(S)                                                                  \
    { i32x4 a, c; const i32x4 zz = {0,0,0,0};                                  \
      a = MFMA64(blo, Bf[S][0], zz); c = MFMA64(bhi, Bf[S][1], zz);            \
      acx0 = a.x + c.x;                                                        \
      a = MFMA64(blo, Bf[S][2], zz); c = MFMA64(bhi, Bf[S][3], zz);            \
      acx1 = a.x + c.x;                                                        \
      a = MFMA64(blo, Bf[S][4], zz); c = MFMA64(bhi, Bf[S][5], zz);            \
      acx2 = a.x + c.x; }

// One recurrence step. Uses current operand set {XC,SCV,MC,CC}; prefetches
// step U+1's h-independent operands into {XN,SN,MN,CN} (PF=1) with the reads
// issued right after the h-frag reads so latency hides under MFMA+pointwise.
#define STEP(U, XC, SCV, MC, CC, XN, SN, MN, CN, PF)                           \
  {                                                                            \
    const char* hsrc = &s_hb8[((U) + 1) & 1][0];                               \
    if (colv){                                                                 \
      blo = *(const uint4*)(hsrc + quad * 16);                                 \
      bhi = *(const uint4*)(hsrc + 64 + quad * 16);                            \
    }                                                                          \
    if (PF){                                                                   \
      int smn = __builtin_amdgcn_readlane(smv, (U) + 1);                       \
      CN = smn & 0xFFFF;                                                       \
      MN = __uint_as_float((unsigned)smn & 0xFFFF0000u);                       \
      if (L < 16){                                                             \
        XN = s_xt[(U) + 1][hi_];                                               \
        SN = s_scl4[CN][hi_];                                                  \
      }                                                                        \
    }                                                                          \
    int acx0, acx1, acx2;                                                      \
    switch (CC){                                                               \
      case 0: MM(0); break;                                                    \
      case 1: MM(1); break;                                                    \
      case 2: MM(2); break;                                                    \
      case 3: MM(3); break;                                                    \
      case 4: MM(4); break;                                                    \
      default: MM(5); break;                                                   \
    }                                                                          \
    if (L < 16){                                                               \
      float ar = fmaf((float)acx0, SCV.x, XC.x);      /* includes x + b_r */   \
      float az = fmaf((float)acx1, SCV.y, XC.y);      /* includes x + b_z */   \
      float an = fmaf((float)acx2, SCV.z, SCV.w);     /* matvec*scl + b_n */   \
      float r = __builtin_amdgcn_rcpf(1.f + __expf(-ar));                      \
      float z = __builtin_amdgcn_rcpf(1.f + __expf(-az));                      \
      float e = __expf(2.f * fmaf(r, an, XC.z));                               \
      float n = fmaf(-2.f, __builtin_amdgcn_rcpf(e + 1.f), 1.f);               \
      float hnew = fmaf(z, hprev - n, n);                                      \
      float ho   = fmaf(MC, hnew - hprev, hprev);                              \
      hprev = ho;                                                              \
      s_hb8[(U) & 1][hi_] = (char)(int)rintf(ho * 127.f);                      \
      s_po[(U)][hi_] = make_float2(wo0r * ho, wo1r * ho);                      \
    }                                                                          \
    lds_barrier();                                                             \
  }

#define REDUCE(TBASE)                                                          \
  {                                                                            \
    int tp = tid >> 4;                                                         \
    int q  = tid & 15;                                                         \
    const f32x4* prow = (const f32x4*)&s_po[tp][0];                            \
    f32x4 a0 = prow[q], a1 = prow[q+16], a2 = prow[q+32], a3 = prow[q+48];     \
    f32x4 sv = (a0 + a1) + (a2 + a3);                                          \
    float p0 = sv.x + sv.z, p1 = sv.y + sv.w;                                  \
    p0 += __shfl_down(p0, 8, 16); p1 += __shfl_down(p1, 8, 16);                \
    p0 += __shfl_down(p0, 4, 16); p1 += __shfl_down(p1, 4, 16);                \
    p0 += __shfl_down(p0, 2, 16); p1 += __shfl_down(p1, 2, 16);                \
    p0 += __shfl_down(p0, 1, 16); p1 += __shfl_down(p1, 1, 16);                \
    if (q == 0)                                                                \
      *(float2*)&outp[((TBASE) + tp) * 2] = make_float2(p0 + bo0, p1 + bo1);   \
  }

  #pragma unroll 1
  for (int ch = 0; ch < 16; ++ch){
    const int t0 = ch << 5;

    // ---- chunk boundary: reduce previous chunk's outputs + build x̃ chunk ----
    if (ch > 0) REDUCE(t0 - 32);
    {
      // x-projection weights scoped here (freed from the step loop's regs)
      unsigned winp[3][4];
      float    binr[3];
      #pragma unroll
      for (int gp = 0; gp < 3; ++gp){
        int row = gp * 128 + hi_p;
        #pragma unroll
        for (int e = 0; e < 4; ++e)
          winp[gp][e] = pack2(Win[(size_t)row * 8 + 2*e], Win[(size_t)row * 8 + 2*e + 1]);
        binr[gp] = binp[row];
      }
      #pragma unroll
      for (int j = 0; j < 8; ++j){
        int tt = t0 + tq * 8 + j;
        uint4 sp = s_stim2[tt];
        int sid_tt = (int)(s_sm[tt] & 0xFFFFu);        // wave-uniform
        float2 brz = s_brz[sid_tt][hi_p];
        float x0 = binr[0];
        x0 = dot2bf(winp[0][0], sp.x, x0); x0 = dot2bf(winp[0][1], sp.y, x0);
        x0 = dot2bf(winp[0][2], sp.z, x0); x0 = dot2bf(winp[0][3], sp.w, x0);
        float x1 = binr[1];
        x1 = dot2bf(winp[1][0], sp.x, x1); x1 = dot2bf(winp[1][1], sp.y, x1);
        x1 = dot2bf(winp[1][2], sp.z, x1); x1 = dot2bf(winp[1][3], sp.w, x1);
        float x2 = binr[2];
        x2 = dot2bf(winp[2][0], sp.x, x2); x2 = dot2bf(winp[2][1], sp.y, x2);
        x2 = dot2bf(winp[2][2], sp.z, x2); x2 = dot2bf(winp[2][3], sp.w, x2);
        f32x4 xv;
        xv.x = x0 + brz.x;          // r-gate bias folded
        xv.y = x1 + brz.y;          // z-gate bias folded
        xv.z = x2;                  // b_n NOT foldable (sits inside r * (...))
        xv.w = 0.f;
        s_xt[tq * 8 + j][hi_p] = xv;
      }
    }
    lds_barrier();                 // x̃ chunk + REDUCE order vs step writes

    smv = (int)s_sm[t0 + (L & 31)];              // this chunk's {mask|sid}

    // prologue: step-0 operands (A set)
    {
      int sm0 = __builtin_amdgcn_readlane(smv, 0);
      scA = sm0 & 0xFFFF;
      mtA = __uint_as_float((unsigned)sm0 & 0xFFFF0000u);
      if (L < 16){
        xtvA  = s_xt[0][hi_];
        sclvA = s_scl4[scA][hi_];
      }
    }

    // steps 0..23: 3 groups of unroll-8 (PF always true)
    #pragma unroll 1
    for (int g = 0; g < 3; ++g){
      const int u0 = g << 3;
      #pragma unroll
      for (int p = 0; p < 4; ++p){
        STEP(u0 + 2*p,     xtvA, sclvA, mtA, scA, xtvB, sclvB, mtB, scB, 1);
        STEP(u0 + 2*p + 1, xtvB, sclvB, mtB, scB, xtvA, sclvA, mtA, scA, 1);
      }
    }
    // steps 24..31: fully unrolled tail; step 31 has no prefetch
    #pragma unroll
    for (int p = 0; p < 3; ++p){
      STEP(24 + 2*p,     xtvA, sclvA, mtA, scA, xtvB, sclvB, mtB, scB, 1);
      STEP(24 + 2*p + 1, xtvB, sclvB, mtB, scB, xtvA, sclvA, mtA, scA, 1);
    }
    STEP(30, xtvA, sclvA, mtA, scA, xtvB, sclvB, mtB, scB, 1);
    STEP(31, xtvB, sclvB, mtB, scB, xtvA, sclvA, mtA, scA, 0);
  }

  // final chunk's outputs
  REDUCE(T_ - 32);
#undef REDUCE
#undef STEP
#undef MM
#undef MFMA64
}

extern "C" void kernel_launch(void* const* d_in, const int* in_sizes, int n_in,
                              void* d_out, int out_size, void* d_ws, size_t ws_size,
                              hipStream_t stream) {
  const float* stim = (const float*)d_in[0];
  const int*   swid = (const int*)  d_in[1];
  const float* mask = (const float*)d_in[2];
  const float* Win  = (const float*)d_in[3];
  const float* binp = (const float*)d_in[4];
  const float* Whr  = (const float*)d_in[5];
  const float* Whz  = (const float*)d_in[6];
  const float* Whn  = (const float*)d_in[7];
  const float* bhr  = (const float*)d_in[8];
  const float* bhz  = (const float*)d_in[9];
  const float* bhn  = (const float*)d_in[10];
  const float* Wo   = (const float*)d_in[11];
  const float* bo   = (const float*)d_in[12];

  uint4* wpk = (uint4*)d_ws;                       // 294912 B packed int8 frags
  float* wsc = (float*)((char*)d_ws + 294912);     // 9216 B row scales

  pack_weights_i8<<<9, 256, 0, stream>>>(Whr, Whz, Whn, wpk, wsc);
  gru_run<<<B_, 512, 0, stream>>>(stim, swid, mask, Win, binp,
                                  bhr, bhz, bhn, Wo, bo, wpk, wsc, (float*)d_out);
}

// Round 12
// 326.461 us; speedup vs baseline: 1.2322x; 1.0289x over previous
//
#include <hip/hip_runtime.h>
#include <stdint.h>

#define B_  256
#define T_  512
#define H_  128
#define NSW 6

typedef __bf16 bf2_t  __attribute__((ext_vector_type(2)));
typedef int    i32x4  __attribute__((ext_vector_type(4)));
typedef float  f32x4  __attribute__((ext_vector_type(4)));

#define LOG2E 1.4426950408889634f

// float -> bf16 round-to-nearest-even
__device__ __forceinline__ unsigned short f2bf(float f){
  unsigned u = __float_as_uint(f);
  unsigned r = u + 0x7FFFu + ((u >> 16) & 1u);
  return (unsigned short)(r >> 16);
}
__device__ __forceinline__ unsigned pack2(float a, float b){
  return (unsigned)f2bf(a) | ((unsigned)f2bf(b) << 16);
}
__device__ __forceinline__ float dot2bf(unsigned wpair, unsigned hpair, float acc){
  return __builtin_amdgcn_fdot2_f32_bf16(__builtin_bit_cast(bf2_t, wpair),
                                         __builtin_bit_cast(bf2_t, hpair), acc, false);
}
__device__ __forceinline__ void lds_barrier(){
  asm volatile("s_waitcnt lgkmcnt(0)\ns_barrier" ::: "memory");
}

// Per-row symmetric int8 quantization into MFMA B-fragment order for
// mfma_i32_16x16x64_i8 (W^T). Tile (s, g', w) covers rows i = 16w..16w+15 of
// gate g'; half m covers k = 64m..64m+63.
// uint4 idx = ((s*24 + g'*8 + w)*2 + m)*64 + q*16 + c holds int8 of
//   W_g'[s][i = 16w + c][k = m*64 + q*16 + e]  (byte e of word e>>2)
// A-side (h) uses the same (quad,byte)<->k convention -> any HW k-permutation
// cancels. scales[s*384 + g'*128 + i] = rowmax / (127*127)
__global__ __launch_bounds__(256) void pack_weights_i8(const float* __restrict__ Wr,
                                                       const float* __restrict__ Wz,
                                                       const float* __restrict__ Wn,
                                                       uint4* __restrict__ dst,
                                                       float* __restrict__ scales){
  int idx = blockIdx.x * 256 + threadIdx.x;     // (s, row384)
  if (idx >= NSW * 384) return;
  int s   = idx / 384;
  int row = idx % 384;
  int gp  = row >> 7;                            // gate 0..2
  int i   = row & 127;                           // output row within gate
  const float* W = (gp == 0) ? Wr : (gp == 1) ? Wz : Wn;
  const float* src = W + (size_t)s * (H_*H_) + (size_t)i * H_;
  float amax = 0.f;
  for (int j = 0; j < H_; ++j) amax = fmaxf(amax, fabsf(src[j]));
  amax = fmaxf(amax, 1e-20f);
  float inv = 127.f / amax;
  scales[idx] = amax / 16129.f;                 // amax / 127^2
  int w = i >> 4, c = i & 15;
  for (int m = 0; m < 2; ++m){
    for (int q = 0; q < 4; ++q){
      unsigned bw[4] = {0, 0, 0, 0};
      for (int e = 0; e < 16; ++e){
        int k = m * 64 + q * 16 + e;
        int v = (int)rintf(src[k] * inv);
        v = v > 127 ? 127 : (v < -127 ? -127 : v);
        bw[e >> 2] |= ((unsigned)(v & 0xFF)) << (8 * (e & 3));
      }
      dst[((size_t)((s * 24 + gp * 8 + w) * 2 + m)) * 64 + q * 16 + c] =
        make_uint4(bw[0], bw[1], bw[2], bw[3]);
    }
  }
}

// 512 threads = 8 waves. Transposed MFMA: A = h (row 0 only), B = W^T.
// Round-12 deltas (serial-chain micro-cuts):
//  - exp2 PRE-SCALING: +-log2e (and the tanh's x2) folded into s_scl4 and
//    x-tilde at init/boundary -> the three chain-muls before v_exp vanish.
//    Pointwise uses __builtin_amdgcn_exp2f directly.
//  - MFMA C-chaining restored (accumulator forwarding is pipelined): drops
//    3 v_add + extractions per step.
//  - DEFERRED s_po write: step U writes step U-1's output partial (hprev IS
//    h_{U-1}) in the post-barrier shadow; pre-barrier drain now covers only
//    the h-byte write. REDUCE moved after the boundary barrier (safe: step-1's
//    s_po[0] write is gated by step-0's barrier, which needs all waves to
//    have finished REDUCE; chunk-0's dead s_po[31] write is zeros).
__global__ __launch_bounds__(512, 2) void gru_run(const float* __restrict__ stim,
    const int*   __restrict__ swid,  const float* __restrict__ mask,
    const float* __restrict__ Win,   const float* __restrict__ binp,
    const float* __restrict__ b_hr,  const float* __restrict__ b_hz, const float* __restrict__ b_hn,
    const float* __restrict__ Wo,    const float* __restrict__ bo,
    const uint4* __restrict__ Wpk,   const float* __restrict__ Wsc,
    float* __restrict__ out)
{
  const int b   = blockIdx.x;
  const int tid = threadIdx.x;
  const int w   = tid >> 6;          // 0..7
  const int L   = tid & 63;

  __shared__ uint4          s_stim2[T_];            // 8 KB   bf16 stim pairs
  __shared__ unsigned       s_sm[T_];               // 2 KB   {bf16 mask <<16 | sid}
  __shared__ __align__(16) float2 s_brz[NSW][H_];     // 6 KB   {b_hr, b_hz} per (s,row)
  __shared__ __align__(16) f32x4  s_scl4[NSW][H_];    // 12 KB  pre-scaled {-k*scl_r,-k*scl_z,2k*scl_n,2k*b_hn}
  __shared__ __align__(16) f32x4  s_xt[32][H_];       // 64 KB  pre-scaled x-projection chunk
  __shared__ __align__(16) float2 s_po[32][130];      // 32.5 KB output partials (padded)
  __shared__ __align__(16) char   s_hb8[2][H_];       // linear int8 h slots

  // ---- init LDS ----
  for (int k = tid; k < T_; k += 512){
    const float* sp = stim + (size_t)b * T_ * 8 + (size_t)k * 8;
    uint4 o;
    o.x = pack2(sp[0], sp[1]); o.y = pack2(sp[2], sp[3]);
    o.z = pack2(sp[4], sp[5]); o.w = pack2(sp[6], sp[7]);
    s_stim2[k] = o;
    int ss = swid[(size_t)b * T_ + k];
    ss = ss < 0 ? 0 : (ss > NSW - 1 ? NSW - 1 : ss);
    s_sm[k] = ((unsigned)f2bf(mask[(size_t)b * T_ + k]) << 16) | (unsigned)ss;
  }
  for (int k = tid; k < NSW * H_; k += 512){
    int s = k >> 7, i = k & 127;
    s_brz[s][i]  = make_float2(b_hr[s * H_ + i], b_hz[s * H_ + i]);
    s_scl4[s][i] = (f32x4){-LOG2E * Wsc[s * 384 + i],
                           -LOG2E * Wsc[s * 384 + 128 + i],
                           2.f * LOG2E * Wsc[s * 384 + 256 + i],
                           2.f * LOG2E * b_hn[s * H_ + i]};
  }
  if (tid < 64) ((int*)s_hb8)[tid] = 0;          // zero both int8 slots

  const int hi_p = tid & 127;
  const int tq   = tid >> 7;                     // 0..3: covers t-offsets tq*8..tq*8+7

  const bool colv = (L & 15) == 0;
  const int  quad = L >> 4;
  const int  hi_  = 16 * w + (L & 15);
  float* outp = out + (size_t)b * T_ * 2;
  const float bo0 = bo[0], bo1 = bo[1];
  float wo0r = 0.f, wo1r = 0.f;
  if (L < 16){ wo0r = Wo[hi_]; wo1r = Wo[H_ + hi_]; }

  // ---- preload ALL 6 switch-sets' B fragments (W^T). volatile: cannot be
  //      sunk into the loop or rematerialized. 6 x 6 x uint4 = 144 regs (AGPR).
  uint4 Bf[6][6];
  #pragma unroll
  for (int s = 0; s < 6; ++s){
    #pragma unroll
    for (int gp = 0; gp < 3; ++gp){
      #pragma unroll
      for (int m = 0; m < 2; ++m){
        const volatile unsigned* vp =
          (const volatile unsigned*)(Wpk + ((size_t)((s * 24 + gp * 8 + w) * 2 + m)) * 64 + L);
        Bf[s][gp*2+m].x = vp[0];
        Bf[s][gp*2+m].y = vp[1];
        Bf[s][gp*2+m].z = vp[2];
        Bf[s][gp*2+m].w = vp[3];
      }
    }
  }

  __syncthreads();

  float hprev = 0.f;
  int   smv = 0;                       // 32 steps of {mask|sid}, lane (L&31) = step
  // persistent rotated operand sets (A = even steps, B = odd steps) and
  // persistent exec-masked registers (zeros written once).
  uint4 blo = {0, 0, 0, 0}, bhi = {0, 0, 0, 0};
  f32x4 xtvA = {0.f,0.f,0.f,0.f}, xtvB = {0.f,0.f,0.f,0.f};
  f32x4 sclvA = {0.f,0.f,0.f,0.f}, sclvB = {0.f,0.f,0.f,0.f};
  float mtA = 0.f, mtB = 0.f;
  int   scA = 0,  scB = 0;

#define MFMA64(A_, B_, C_) __builtin_amdgcn_mfma_i32_16x16x64_i8( \
    __builtin_bit_cast(i32x4, (A_)), __builtin_bit_cast(i32x4, (B_)), (C_), 0, 0, 0)
#define MM(S)                                                                  \
    { i32x4 a; const i32x4 zz = {0,0,0,0};                                     \
      a = MFMA64(blo, Bf[S][0], zz); a = MFMA64(bhi, Bf[S][1], a); acx0 = a.x; \
      a = MFMA64(blo, Bf[S][2], zz); a = MFMA64(bhi, Bf[S][3], a); acx1 = a.x; \
      a = MFMA64(blo, Bf[S][4], zz); a = MFMA64(bhi, Bf[S][5], a); acx2 = a.x; }

// One recurrence step. Uses current operand set {XC,SCV,MC,CC}; prefetches
// step U+1's h-independent operands into {XN,SN,MN,CN} (PF=1). The DEFERRED
// s_po write for step U-1 (hprev == h_{U-1}) lands in the post-barrier shadow.
#define STEP(U, XC, SCV, MC, CC, XN, SN, MN, CN, PF)                           \
  {                                                                            \
    const char* hsrc = &s_hb8[((U) + 1) & 1][0];                               \
    if (colv){                                                                 \
      blo = *(const uint4*)(hsrc + quad * 16);                                 \
      bhi = *(const uint4*)(hsrc + 64 + quad * 16);                            \
    }                                                                          \
    if ((U) > 0 && L < 16)                                                     \
      s_po[(U) - 1][hi_] = make_float2(wo0r * hprev, wo1r * hprev);            \
    if (PF){                                                                   \
      int smn = __builtin_amdgcn_readlane(smv, (U) + 1);                       \
      CN = smn & 0xFFFF;                                                       \
      MN = __uint_as_float((unsigned)smn & 0xFFFF0000u);                       \
      if (L < 16){                                                             \
        XN = s_xt[(U) + 1][hi_];                                               \
        SN = s_scl4[CN][hi_];                                                  \
      }                                                                        \
    }                                                                          \
    int acx0, acx1, acx2;                                                      \
    switch (CC){                                                               \
      case 0: MM(0); break;                                                    \
      case 1: MM(1); break;                                                    \
      case 2: MM(2); break;                                                    \
      case 3: MM(3); break;                                                    \
      case 4: MM(4); break;                                                    \
      default: MM(5); break;                                                   \
    }                                                                          \
    if (L < 16){                                                               \
      float ar = fmaf((float)acx0, SCV.x, XC.x);   /* -log2e*(pre-act r) */    \
      float az = fmaf((float)acx1, SCV.y, XC.y);   /* -log2e*(pre-act z) */    \
      float an = fmaf((float)acx2, SCV.z, SCV.w);  /* 2log2e*(Wh*scl + b_n) */ \
      float r = __builtin_amdgcn_rcpf(1.f + __builtin_amdgcn_exp2f(ar));       \
      float z = __builtin_amdgcn_rcpf(1.f + __builtin_amdgcn_exp2f(az));       \
      float e = __builtin_amdgcn_exp2f(fmaf(r, an, XC.z));                     \
      float n = fmaf(-2.f, __builtin_amdgcn_rcpf(e + 1.f), 1.f);               \
      float hnew = fmaf(z, hprev - n, n);                                      \
      float ho   = fmaf(MC, hnew - hprev, hprev);                              \
      hprev = ho;                                                              \
      s_hb8[(U) & 1][hi_] = (char)(int)rintf(ho * 127.f);                      \
    }                                                                          \
    lds_barrier();                                                             \
  }

#define REDUCE(TBASE)                                                          \
  {                                                                            \
    int tp = tid >> 4;                                                         \
    int q  = tid & 15;                                                         \
    const f32x4* prow = (const f32x4*)&s_po[tp][0];                            \
    f32x4 a0 = prow[q], a1 = prow[q+16], a2 = prow[q+32], a3 = prow[q+48];     \
    f32x4 sv = (a0 + a1) + (a2 + a3);                                          \
    float p0 = sv.x + sv.z, p1 = sv.y + sv.w;                                  \
    p0 += __shfl_down(p0, 8, 16); p1 += __shfl_down(p1, 8, 16);                \
    p0 += __shfl_down(p0, 4, 16); p1 += __shfl_down(p1, 4, 16);                \
    p0 += __shfl_down(p0, 2, 16); p1 += __shfl_down(p1, 2, 16);                \
    p0 += __shfl_down(p0, 1, 16); p1 += __shfl_down(p1, 1, 16);                \
    if (q == 0)                                                                \
      *(float2*)&outp[((TBASE) + tp) * 2] = make_float2(p0 + bo0, p1 + bo1);   \
  }

  #pragma unroll 1
  for (int ch = 0; ch < 16; ++ch){
    const int t0 = ch << 5;

    // deferred step-31 partial of the PREVIOUS chunk (hprev == h_31).
    // At ch==0 this writes zeros to s_po[31] -- dead (REDUCE skipped).
    if (L < 16)
      s_po[31][hi_] = make_float2(wo0r * hprev, wo1r * hprev);

    // ---- chunk boundary: build x̃ chunk (pre-scaled, biases folded) ----
    {
      unsigned winp[3][4];
      float    binr[3];
      #pragma unroll
      for (int gp = 0; gp < 3; ++gp){
        int row = gp * 128 + hi_p;
        #pragma unroll
        for (int e = 0; e < 4; ++e)
          winp[gp][e] = pack2(Win[(size_t)row * 8 + 2*e], Win[(size_t)row * 8 + 2*e + 1]);
        binr[gp] = binp[row];
      }
      #pragma unroll
      for (int j = 0; j < 8; ++j){
        int tt = t0 + tq * 8 + j;
        uint4 sp = s_stim2[tt];
        int sid_tt = (int)(s_sm[tt] & 0xFFFFu);        // wave-uniform
        float2 brz = s_brz[sid_tt][hi_p];
        float x0 = binr[0];
        x0 = dot2bf(winp[0][0], sp.x, x0); x0 = dot2bf(winp[0][1], sp.y, x0);
        x0 = dot2bf(winp[0][2], sp.z, x0); x0 = dot2bf(winp[0][3], sp.w, x0);
        float x1 = binr[1];
        x1 = dot2bf(winp[1][0], sp.x, x1); x1 = dot2bf(winp[1][1], sp.y, x1);
        x1 = dot2bf(winp[1][2], sp.z, x1); x1 = dot2bf(winp[1][3], sp.w, x1);
        float x2 = binr[2];
        x2 = dot2bf(winp[2][0], sp.x, x2); x2 = dot2bf(winp[2][1], sp.y, x2);
        x2 = dot2bf(winp[2][2], sp.z, x2); x2 = dot2bf(winp[2][3], sp.w, x2);
        f32x4 xv;
        xv.x = -LOG2E * (x0 + brz.x);       // r: bias folded + exp2 pre-scale
        xv.y = -LOG2E * (x1 + brz.y);       // z: bias folded + exp2 pre-scale
        xv.z = (2.f * LOG2E) * x2;          // n: exp2 pre-scale (b_n in sclv.w)
        xv.w = 0.f;
        s_xt[tq * 8 + j][hi_p] = xv;
      }
    }
    lds_barrier();                 // x̃ chunk + deferred s_po[31] visible

    // previous chunk's outputs (after the barrier; safe vs step-1's s_po[0]
    // write, which is gated by step-0's barrier)
    if (ch > 0) REDUCE(t0 - 32);

    smv = (int)s_sm[t0 + (L & 31)];              // this chunk's {mask|sid}

    // prologue: step-0 operands (A set)
    {
      int sm0 = __builtin_amdgcn_readlane(smv, 0);
      scA = sm0 & 0xFFFF;
      mtA = __uint_as_float((unsigned)sm0 & 0xFFFF0000u);
      if (L < 16){
        xtvA  = s_xt[0][hi_];
        sclvA = s_scl4[scA][hi_];
      }
    }

    // steps 0..23: 3 groups of unroll-8 (PF always true)
    #pragma unroll 1
    for (int g = 0; g < 3; ++g){
      const int u0 = g << 3;
      #pragma unroll
      for (int p = 0; p < 4; ++p){
        STEP(u0 + 2*p,     xtvA, sclvA, mtA, scA, xtvB, sclvB, mtB, scB, 1);
        STEP(u0 + 2*p + 1, xtvB, sclvB, mtB, scB, xtvA, sclvA, mtA, scA, 1);
      }
    }
    // steps 24..31: fully unrolled tail; step 31 has no prefetch
    #pragma unroll
    for (int p = 0; p < 3; ++p){
      STEP(24 + 2*p,     xtvA, sclvA, mtA, scA, xtvB, sclvB, mtB, scB, 1);
      STEP(24 + 2*p + 1, xtvB, sclvB, mtB, scB, xtvA, sclvA, mtA, scA, 1);
    }
    STEP(30, xtvA, sclvA, mtA, scA, xtvB, sclvB, mtB, scB, 1);
    STEP(31, xtvB, sclvB, mtB, scB, xtvA, sclvA, mtA, scA, 0);
  }

  // final chunk: deferred step-31 partial, then reduce
  if (L < 16)
    s_po[31][hi_] = make_float2(wo0r * hprev, wo1r * hprev);
  lds_barrier();
  REDUCE(T_ - 32);
#undef REDUCE
#undef STEP
#undef MM
#undef MFMA64
}

extern "C" void kernel_launch(void* const* d_in, const int* in_sizes, int n_in,
                              void* d_out, int out_size, void* d_ws, size_t ws_size,
                              hipStream_t stream) {
  const float* stim = (const float*)d_in[0];
  const int*   swid = (const int*)  d_in[1];
  const float* mask = (const float*)d_in[2];
  const float* Win  = (const float*)d_in[3];
  const float* binp = (const float*)d_in[4];
  const float* Whr  = (const float*)d_in[5];
  const float* Whz  = (const float*)d_in[6];
  const float* Whn  = (const float*)d_in[7];
  const float* bhr  = (const float*)d_in[8];
  const float* bhz  = (const float*)d_in[9];
  const float* bhn  = (const float*)d_in[10];
  const float* Wo   = (const float*)d_in[11];
  const float* bo   = (const float*)d_in[12];

  uint4* wpk = (uint4*)d_ws;                       // 294912 B packed int8 frags
  float* wsc = (float*)((char*)d_ws + 294912);     // 9216 B row scales

  pack_weights_i8<<<9, 256, 0, stream>>>(Whr, Whz, Whn, wpk, wsc);
  gru_run<<<B_, 512, 0, stream>>>(stim, swid, mask, Win, binp,
                                  bhr, bhz, bhn, Wo, bo, wpk, wsc, (float*)d_out);
}